// Round 1
// baseline (2343.061 us; speedup 1.0000x reference)
//
#include <hip/hip_runtime.h>
#include <math.h>

// KanLayer: out[o] = sum_i sum_k c[i,o,k] * B[i,k]
// x: (2048,) fp32 in [0,1); c: (2048, 4096, 61) fp32; out: (4096,) fp32.
// B is a DEGREE-2 (quadratic) B-spline basis (the reference loop runs p=1..2),
// so each row B[i,:] has at most 3 nonzero entries at k = j-2..j where
// t_j <= x_i < t_{j+1}, truncated to k <= 60 at the right edge.
// => only 12 of every 244 bytes of c are needed; we do scattered 12B reads
// instead of streaming the full 2.05 GB.

#define INPUT_DIM 2048
#define OUT_DIM   4096
#define N_COEF    61
#define IC        16    // i's per block (grid.y = 2048/16 = 128)
#define OB        256   // o's per block (grid.x = 4096/256 = 16)

__device__ __forceinline__ float Tk(int k) {
    // matches jnp.linspace(-1, 1, 64) to within 1 ulp; B-splines are C1
    // continuous so off-by-ulp interval selection is numerically harmless.
    return -1.0f + (float)k * (2.0f / 63.0f);
}

__global__ void kan_zero_kernel(float* __restrict__ out) {
    out[blockIdx.x * blockDim.x + threadIdx.x] = 0.0f;
}

__global__ __launch_bounds__(OB) void kan_kernel(const float* __restrict__ x,
                                                 const float* __restrict__ c,
                                                 float* __restrict__ out) {
    __shared__ int   sk0[IC];
    __shared__ float sw0[IC], sw1[IC], sw2[IC];

    const int tid    = threadIdx.x;
    const int i_base = blockIdx.y * IC;

    if (tid < IC) {
        const float xv = x[i_base + tid];
        // interval index j: t_j <= xv < t_{j+1}
        int j = (int)floorf((xv + 1.0f) * 31.5f);
        j = max(0, min(62, j));
        while (j > 0  && xv <  Tk(j))     --j;   // <=1 iter fixups
        while (j < 62 && xv >= Tk(j + 1)) ++j;

        const float tjm1 = Tk(j - 1), tj = Tk(j), tj1 = Tk(j + 1), tj2 = Tk(j + 2);
        // Cox-de Boor, degree 1 then degree 2 (exactly the reference recursion
        // restricted to the nonzero entries):
        const float b1l = (tj1 - xv) / (tj1 - tj);   // B1_{j-1}
        const float b1r = (xv - tj)  / (tj1 - tj);   // B1_j
        const float w0 = (tj1 - xv) / (tj1 - tjm1) * b1l;                       // B2_{j-2}
        const float w1 = (xv - tjm1) / (tj1 - tjm1) * b1l
                       + (tj2 - xv) / (tj2 - tj)    * b1r;                      // B2_{j-1}
        const float w2 = (xv - tj)  / (tj2 - tj)    * b1r;                      // B2_j

        // Right-edge truncation: B has only 61 entries (k <= 60). For j=61
        // drop w2; for j=62 keep only w0 (at k=60). Shift weights right by s
        // so we always address k0..k0+2 with k0+2 <= 60.
        int s = j - 60; if (s < 0) s = 0;
        float wsrc[3] = {w0, w1, w2};
        float ww[3]   = {0.0f, 0.0f, 0.0f};
        #pragma unroll
        for (int m = 0; m < 3; ++m) {
            const int l = m + s;
            if (l < 3) ww[l] = wsrc[m];
        }
        sk0[tid] = j - 2 - s;
        sw0[tid] = ww[0];
        sw1[tid] = ww[1];
        sw2[tid] = ww[2];
    }
    __syncthreads();

    const int o = blockIdx.x * OB + tid;
    const long long stride_i = (long long)OUT_DIM * N_COEF;  // 249856
    const float* pbase = c + (long long)i_base * stride_i + (long long)o * N_COEF;

    float acc = 0.0f;
    #pragma unroll
    for (int ii = 0; ii < IC; ++ii) {
        const float* p = pbase + (long long)ii * stride_i + sk0[ii];
        acc = fmaf(p[0], sw0[ii], acc);
        acc = fmaf(p[1], sw1[ii], acc);
        acc = fmaf(p[2], sw2[ii], acc);
    }
    atomicAdd(&out[o], acc);
}

extern "C" void kernel_launch(void* const* d_in, const int* in_sizes, int n_in,
                              void* d_out, int out_size, void* d_ws, size_t ws_size,
                              hipStream_t stream) {
    const float* x   = (const float*)d_in[0];
    const float* c   = (const float*)d_in[1];
    float*       out = (float*)d_out;

    hipLaunchKernelGGL(kan_zero_kernel, dim3(OUT_DIM / 256), dim3(256), 0, stream, out);

    dim3 grid(OUT_DIM / OB, INPUT_DIM / IC);   // 16 x 128 = 2048 blocks
    hipLaunchKernelGGL(kan_kernel, grid, dim3(OB), 0, stream, x, c, out);
}